// Round 4
// baseline (4917.501 us; speedup 1.0000x reference)
//
#include <hip/hip_runtime.h>
#include <cmath>

#define D_K 768
#define GK 640
#define KC_N 24           // 768/32 k-chunks
#define HALF_TILE 10240   // halves: 20 nc * 64 lanes * 8
#define TILE_HALVES 20480 // hi+lo tile per (kc, group) = 40960 B

typedef _Float16 f16x8 __attribute__((ext_vector_type(8)));
typedef float f32x4 __attribute__((ext_vector_type(4)));

typedef __attribute__((address_space(1))) const void* as1cv;
typedef __attribute__((address_space(3))) void* as3v;

// ---------------- prep: zero bins + swizzle W + convert x to f16 hi/lo A-frags ----------------
// WB layout: [kc][g][h(hi/lo)][ncl(20)][lane(64)][j(8)] halves.
// XH/XL layout: [rt(2048)][kc(24)][lane(64)][j(8)] halves, where
//   element = x[rt*16 + (lane&15)][kc*32 + (lane>>4)*8 + j]  (16x16x32 A-frag order)
__global__ __launch_bounds__(256) void prep_kernel(const float* __restrict__ W,
        const float* __restrict__ x, unsigned* __restrict__ bins,
        _Float16* __restrict__ WB, _Float16* __restrict__ XH, _Float16* __restrict__ XL) {
    int tid = threadIdx.x, bid = blockIdx.x;
    int t = bid * 256 + tid;
    if (t < 1281) bins[t] = 0u;      // counts[640] + probsum[640] + ticket[1]
    int l = tid & 63;
    if (bid < 240) {                 // W swizzle: 960 frags
        int fid = bid * 4 + (tid >> 6);
        int kc = fid / 40, nc = fid - kc * 40;
        int g = nc / 20, ncl = nc - g * 20;
        int n = nc * 16 + (l & 15);
        int k0 = kc * 32 + (l >> 4) * 8;
        f16x8 hi, lo;
#pragma unroll
        for (int j = 0; j < 8; ++j) {
            float wv = W[(size_t)(k0 + j) * GK + n];
            _Float16 h = (_Float16)wv;
            hi[j] = h;
            lo[j] = (_Float16)(wv - (float)h);
        }
        size_t base = (size_t)(kc * 2 + g) * TILE_HALVES + ncl * 512 + l * 8;
        *(f16x8*)(WB + base) = hi;
        *(f16x8*)(WB + base + HALF_TILE) = lo;
    } else {                         // x convert: 49152 frags (2048 row-tiles x 24 kc)
        int fid = (bid - 240) * 4 + (tid >> 6);
        int rt = fid / 24, kc = fid - rt * 24;
        const float* xp = x + (size_t)(rt * 16 + (l & 15)) * D_K + kc * 32 + (l >> 4) * 8;
        f32x4 v0 = *(const f32x4*)xp, v1 = *(const f32x4*)(xp + 4);
        f16x8 hi, lo;
#pragma unroll
        for (int j = 0; j < 4; ++j) {
            float f; _Float16 h;
            f = v0[j]; h = (_Float16)f; hi[j] = h;     lo[j] = (_Float16)(f - (float)h);
            f = v1[j]; h = (_Float16)f; hi[4 + j] = h; lo[4 + j] = (_Float16)(f - (float)h);
        }
        size_t base = (size_t)fid * 512 + l * 8;
        *(f16x8*)(XH + base) = hi;
        *(f16x8*)(XL + base) = lo;
    }
}

// ---------------- main: 64 rows x 320 cols (one group) per block, 4 waves ----------------
// wave w: ALL 64 rows (4 m-chunks) x col slice w*80..+79. acc[4][5] per wave.
// B double-buffered in LDS (2 x 40960); one barrier per kc. Stage(kc+1) + A(kc+1) issued
// right AFTER the barrier -> drained at the NEXT barrier (a full MFMA phase later): no
// fresh-load drain ever. A comes pre-converted (XH/XL) -> no VALU convert in the loop.
// fin fused: last block (device ticket) computes perplexities.
__global__ __launch_bounds__(256, 2) void main_kernel(
        const _Float16* __restrict__ XH, const _Float16* __restrict__ XL,
        const float* __restrict__ bias, const float* __restrict__ noise,
        const float* __restrict__ cb, const _Float16* __restrict__ WB,
        float* __restrict__ out, unsigned* __restrict__ counts, float* __restrict__ probsum,
        unsigned* __restrict__ ticket, float* __restrict__ out2)
{
    __shared__ __align__(16) char smem[81920];            // 2 x 40960 B double-buffer
    // epilogue overlays (valid only after final K-loop barrier; live in buf0 region,
    // disjoint from buf1 which the last iteration reads):
    float (*s_pmax)[64]  = (float(*)[64])(smem);          // [4][64]
    int   (*s_pcol)[64]  = (int(*)[64])(smem + 1024);
    float (*s_pgmax)[64] = (float(*)[64])(smem + 2048);
    int   (*s_pgcol)[64] = (int(*)[64])(smem + 3072);
    float (*s_psum)[64]  = (float(*)[64])(smem + 4096);
    float* s_fmax  = (float*)(smem + 5120);
    float* s_fsum  = (float*)(smem + 5376);
    int*   s_fgcol = (int*)(smem + 5632);
    float* s_bins  = (float*)(smem + 5888);               // 1280 B, ends 7168
    int*   s_last  = (int*)(smem + 7168);
    float* s_red   = (float*)(smem + 7184);               // 4 floats

    int tid = threadIdx.x;
    int bx = blockIdx.x;
    int g  = (bx >> 3) & 1;                  // group 0/1; g-pair lands on same XCD
    int rb = (bx & 7) | ((bx >> 4) << 3);    // row-stripe 0..511 (bijective remap)
    int r0 = rb * 64;
    int w = tid >> 6;        // wave 0..3 = col slice
    int l = tid & 63;
    int lrow = l >> 4;       // quad 0..3
    int lcol = l & 15;
    int s5 = w * 5;

    f32x4 acc[4][5];
#pragma unroll
    for (int i = 0; i < 4; ++i)
#pragma unroll
        for (int j = 0; j < 5; ++j) acc[i][j] = (f32x4){0.f, 0.f, 0.f, 0.f};

    // A-frag base: frag (rt0+i, kc) at XH + ((rt0+i)*24 + kc)*512 + l*8
    size_t xbase = ((size_t)(rb * 4) * 24) * 512 + (size_t)l * 8;
    const _Float16* xh = XH + xbase;
    const _Float16* xl = XL + xbase;

    // async stage of the (kc, g) B tile into buffer buf: 40960 B = 2560 x 16 B, 10/thread
    auto stage = [&](int kc, int buf) {
        const char* src = (const char*)(WB + (size_t)(kc * 2 + g) * TILE_HALVES);
        char* dst = smem + buf * 40960;
#pragma unroll
        for (int kk = 0; kk < 10; ++kk) {
            int u = tid + kk * 256;
            __builtin_amdgcn_global_load_lds((as1cv)(src + (size_t)u * 16),
                                             (as3v)(dst + u * 16), 16, 0, 0);
        }
    };

    f16x8 ahb[2][4], alb[2][4];
    stage(0, 0);
#pragma unroll
    for (int i = 0; i < 4; ++i) {
        ahb[0][i] = *(const f16x8*)(xh + (i * 24 + 0) * 512);
        alb[0][i] = *(const f16x8*)(xl + (i * 24 + 0) * 512);
    }

#pragma unroll 2
    for (int kc = 0; kc < KC_N; ++kc) {
        int cur = kc & 1;
        __syncthreads();    // buf[cur] staged (vmcnt drain of ops issued a full iter ago);
                            // prior iteration's readers of buf[cur^1] are done
        if (kc < KC_N - 1) {
            stage(kc + 1, cur ^ 1);
#pragma unroll
            for (int i = 0; i < 4; ++i) {
                ahb[(kc + 1) & 1][i] = *(const f16x8*)(xh + (i * 24 + kc + 1) * 512);
                alb[(kc + 1) & 1][i] = *(const f16x8*)(xl + (i * 24 + kc + 1) * 512);
            }
        }
        const _Float16* sBc = (const _Float16*)(smem + cur * 40960);
#pragma unroll
        for (int j = 0; j < 5; ++j) {
            f16x8 bh = *(const f16x8*)(sBc + (s5 + j) * 512 + l * 8);
            f16x8 bl = *(const f16x8*)(sBc + HALF_TILE + (s5 + j) * 512 + l * 8);
#pragma unroll
            for (int i = 0; i < 4; ++i) {
                acc[i][j] = __builtin_amdgcn_mfma_f32_16x16x32_f16(ahb[cur][i], bh, acc[i][j], 0, 0, 0);
                acc[i][j] = __builtin_amdgcn_mfma_f32_16x16x32_f16(alb[cur][i], bh, acc[i][j], 0, 0, 0);
                acc[i][j] = __builtin_amdgcn_mfma_f32_16x16x32_f16(ahb[cur][i], bl, acc[i][j], 0, 0, 0);
            }
        }
    }

    // bias (zeros in setup, kept for correctness)
#pragma unroll
    for (int j = 0; j < 5; ++j) {
        float bb = bias[g * 320 + (s5 + j) * 16 + lcol];
#pragma unroll
        for (int i = 0; i < 4; ++i)
#pragma unroll
            for (int r = 0; r < 4; ++r) acc[i][j][r] += bb;
    }

    // ---------------- epilogue (one group per block; cols local 0..319) ----------------
    // E1: per-wave (max,argmax) of logits and logits+gumbel over this wave's 80-col slice
#pragma unroll
    for (int i = 0; i < 4; ++i) {
#pragma unroll
        for (int r = 0; r < 4; ++r) {
            int row = i * 16 + lrow * 4 + r;     // C/D: row = quad*4 + reg, col = lane&15
            float vmax = -3.4e38f; int vcol = 0;
            float gmax = -3.4e38f; int gcol = 0;
            const float* np = noise + (size_t)(r0 + row) * GK + g * 320 + s5 * 16 + lcol;
#pragma unroll
            for (int j = 0; j < 5; ++j) {
                float v = acc[i][j][r];
                int c = (s5 + j) * 16 + lcol;
                if (v > vmax) { vmax = v; vcol = c; }
                float u = np[j * 16] * (1.0f - 2e-6f) + 1e-6f;
                float gn = -__logf(-__logf(u));
                float z = v + gn;    // argmax((logits+g)/TAU) == argmax(logits+g)
                if (z > gmax) { gmax = z; gcol = c; }
            }
#pragma unroll
            for (int off = 1; off < 16; off <<= 1) {
                float ov = __shfl_xor(vmax, off); int oc = __shfl_xor(vcol, off);
                if (ov > vmax || (ov == vmax && oc < vcol)) { vmax = ov; vcol = oc; }
                float og = __shfl_xor(gmax, off); int ogc = __shfl_xor(gcol, off);
                if (og > gmax || (og == gmax && ogc < gcol)) { gmax = og; gcol = ogc; }
            }
            if (lcol == 0) {
                s_pmax[w][row] = vmax; s_pcol[w][row] = vcol;
                s_pgmax[w][row] = gmax; s_pgcol[w][row] = gcol;
            }
        }
    }
    s_bins[tid] = 0.0f;
    if (tid < 64) s_bins[256 + tid] = 0.0f;
    __syncthreads();

    // E2: combine 4 slices per row in ascending-col order (reference tie-break)
    if (tid < 64) {
        int row = tid;
        float vmax = -3.4e38f; int vcol = 0;
        float gmax = -3.4e38f; int gcol = 0;
        for (int ss = 0; ss < 4; ++ss) {
            float v = s_pmax[ss][row];
            if (v > vmax) { vmax = v; vcol = s_pcol[ss][row]; }
            float z = s_pgmax[ss][row];
            if (z > gmax) { gmax = z; gcol = s_pgcol[ss][row]; }
        }
        s_fmax[row] = vmax;
        s_fgcol[row] = gcol;
        atomicAdd(&counts[g * 320 + vcol], 1u);
    }
    __syncthreads();

    // E3: exp-sum per row
#pragma unroll
    for (int i = 0; i < 4; ++i) {
#pragma unroll
        for (int r = 0; r < 4; ++r) {
            int row = i * 16 + lrow * 4 + r;
            float M = s_fmax[row];
            float sm = 0.f;
#pragma unroll
            for (int j = 0; j < 5; ++j) sm += __expf(acc[i][j][r] - M);
#pragma unroll
            for (int off = 1; off < 16; off <<= 1) sm += __shfl_xor(sm, off);
            if (lcol == 0) s_psum[w][row] = sm;
        }
    }
    __syncthreads();
    if (tid < 64) {
        float S = 0.f;
        for (int ss = 0; ss < 4; ++ss) S += s_psum[ss][tid];
        s_fsum[tid] = S;
    }
    __syncthreads();

    // E4: per-thread register partials per column, quad-combine via shfl, one
    // collision-free 16-lane LDS atomic per j
    {
        float part[5] = {0.f, 0.f, 0.f, 0.f, 0.f};
#pragma unroll
        for (int i = 0; i < 4; ++i) {
#pragma unroll
            for (int r = 0; r < 4; ++r) {
                int row = i * 16 + lrow * 4 + r;
                float M = s_fmax[row];
                float invS = 1.0f / s_fsum[row];
#pragma unroll
                for (int j = 0; j < 5; ++j)
                    part[j] += __expf(acc[i][j][r] - M) * invS;
            }
        }
#pragma unroll
        for (int j = 0; j < 5; ++j) {
            float p = part[j];
            p += __shfl_xor(p, 16);
            p += __shfl_xor(p, 32);
            if (lrow == 0) atomicAdd(&s_bins[(s5 + j) * 16 + lcol], p);
        }
    }
    __syncthreads();
    atomicAdd(&probsum[g * 320 + tid], s_bins[tid]);
    if (tid < 64) atomicAdd(&probsum[g * 320 + 256 + tid], s_bins[256 + tid]);

    // E5: out[row, g*128:(g+1)*128] = cb[winner, :]  (y == y_hard in forward)
    {
        int row = tid >> 2, jj = tid & 3;    // 64 rows x 4 threads
        int wcol = g * 320 + s_fgcol[row];
        const f32x4* src = (const f32x4*)(cb + (size_t)wcol * 128);
        f32x4* dst = (f32x4*)(out + (size_t)(r0 + row) * 256 + g * 128);
#pragma unroll
        for (int k = 0; k < 8; ++k) dst[k * 4 + jj] = src[k * 4 + jj];
    }

    // ---------------- fused finalize: last block computes perplexities ----------------
    __syncthreads();                 // all this block's global atomics complete (vmcnt drained)
    if (tid == 0) {
        __threadfence();
        unsigned prev = atomicAdd(ticket, 1u);
        *s_last = (prev == 1023u) ? 1 : 0;
    }
    __syncthreads();
    if (*s_last) {
        __threadfence();
        // wave w -> segment: 0:hard g0, 1:hard g1, 2:soft g0, 3:soft g1
        float v = 0.f;
#pragma unroll
        for (int k = 0; k < 5; ++k) {
            int idx = (w & 1) * 320 + l + 64 * k;
            float p;
            if (w < 2)
                p = (float)__hip_atomic_load(&counts[idx], __ATOMIC_RELAXED,
                                             __HIP_MEMORY_SCOPE_AGENT) * (1.0f / 32768.0f);
            else
                p = __hip_atomic_load(&probsum[idx], __ATOMIC_RELAXED,
                                      __HIP_MEMORY_SCOPE_AGENT) * (1.0f / 32768.0f);
            v += p * logf(p + 1e-7f);
        }
#pragma unroll
        for (int off = 1; off < 64; off <<= 1) v += __shfl_xor(v, off);
        if (l == 0) s_red[w] = v;
        __syncthreads();
        if (tid < 2) out2[tid] = expf(-s_red[tid * 2]) + expf(-s_red[tid * 2 + 1]);
    }
}

extern "C" void kernel_launch(void* const* d_in, const int* in_sizes, int n_in,
                              void* d_out, int out_size, void* d_ws, size_t ws_size,
                              hipStream_t stream) {
    const float* x     = (const float*)d_in[0];   // [16,2048,768]
    const float* W     = (const float*)d_in[1];   // [768,640]
    const float* b     = (const float*)d_in[2];   // [640]
    const float* cb    = (const float*)d_in[3];   // [1,640,128]
    const float* noise = (const float*)d_in[4];   // [32768,2,320]
    float* out = (float*)d_out;                   // 16*2048*256 floats + 2 scalars

    char* ws = (char*)d_ws;
    unsigned* counts = (unsigned*)ws;             // [640] u32
    float* probsum   = (float*)(ws + 2560);       // [640] f32
    unsigned* ticket = (unsigned*)(ws + 5120);    // [1]  u32 (word 1280 of zeroed range)
    _Float16* WB     = (_Float16*)(ws + 8192);                // 1,966,080 B
    _Float16* XH     = (_Float16*)(ws + 1974272);             // 50,331,648 B
    _Float16* XL     = (_Float16*)(ws + 1974272 + 50331648);  // 50,331,648 B (end ~102.6 MB)

    hipLaunchKernelGGL(prep_kernel, dim3(12528), dim3(256), 0, stream, W, x, counts, WB, XH, XL);
    hipLaunchKernelGGL(main_kernel, dim3(1024), dim3(256), 0, stream,
                       XH, XL, b, noise, cb, WB, out, counts, probsum, ticket, out + 8388608);
}

// Round 5
// 389.689 us; speedup vs baseline: 12.6191x; 12.6191x over previous
//
#include <hip/hip_runtime.h>
#include <cmath>

#define D_K 768
#define GK 640
#define KC_N 24           // 768/32 k-chunks
#define HALF_TILE 10240   // halves: 20 nc * 64 lanes * 8
#define TILE_HALVES 20480 // hi+lo tile per (kc, group) = 40960 B

typedef _Float16 f16x8 __attribute__((ext_vector_type(8)));
typedef float f32x4 __attribute__((ext_vector_type(4)));

typedef __attribute__((address_space(1))) const void* as1cv;
typedef __attribute__((address_space(3))) void* as3v;

// ---------------- prep: zero bins+ticket + swizzle W (fp32 -> fp16 hi/lo, MFMA B-frag order) ----
// WB layout: [kc][g][h(hi/lo)][ncl(20)][lane(64)][j(8)] halves.
// lane supplies B[k = kc*32 + (lane>>4)*8 + j][n = (g*20+ncl)*16 + (lane&15)]
__global__ __launch_bounds__(256) void prep_kernel(const float* __restrict__ W,
        unsigned* __restrict__ bins, _Float16* __restrict__ WB) {
    int t = blockIdx.x * 256 + threadIdx.x;   // 240*256 = 61440 = 960 frags * 64 lanes
    if (t < 1344) bins[t] = 0u;               // counts[640] + probsum[640] + ticket
    int fid = t >> 6;
    int l = t & 63;
    int kc = fid / 40, nc = fid - kc * 40;
    int g = nc / 20, ncl = nc - g * 20;
    int n = nc * 16 + (l & 15);
    int k0 = kc * 32 + (l >> 4) * 8;
    f16x8 hi, lo;
#pragma unroll
    for (int j = 0; j < 8; ++j) {
        float wv = W[(size_t)(k0 + j) * GK + n];
        _Float16 h = (_Float16)wv;
        hi[j] = h;
        lo[j] = (_Float16)(wv - (float)h);
    }
    size_t base = (size_t)(kc * 2 + g) * TILE_HALVES + ncl * 512 + l * 8;
    *(f16x8*)(WB + base) = hi;
    *(f16x8*)(WB + base + HALF_TILE) = lo;
}

// ---------------- main: 64 rows x 320 cols (one group) per block, 8 waves ----------------
// wave w: mch = w>>2 (rows mch*32..+31, 2 chunks of 16), slice s = w&3 (cols s*80..+79).
// B double-buffered in LDS (2 x 40960 B), ONE barrier per kc: stage(kc+1)+A-prefetch issued
// right after the barrier, drained at the NEXT barrier -> a full MFMA phase of latency cover.
// Epilogue LDS arrays overlay buf0 (last iteration kc=23 reads buf1; buf0's readers finished
// at the top-of-23 barrier). 81920 B/block -> 2 blocks/CU, anti-phase overlap.
// fin fused: last block (device ticket) computes perplexities (saves ~100us fixed overhead).
__global__ __launch_bounds__(512, 4) void main_kernel(
        const float* __restrict__ x, const float* __restrict__ bias,
        const float* __restrict__ noise, const float* __restrict__ cb,
        const _Float16* __restrict__ WB,
        float* __restrict__ out, unsigned* __restrict__ counts, float* __restrict__ probsum,
        unsigned* __restrict__ ticket, float* __restrict__ out2)
{
    __shared__ __align__(16) char smem[81920];            // 2 x 40960 B double-buffer
    // epilogue overlays (valid only after the final K-loop barrier; live in buf0):
    float (*s_pmax)[64]  = (float(*)[64])(smem);          // 1024 B
    int   (*s_pcol)[64]  = (int(*)[64])(smem + 1024);     // 1024 B
    float (*s_pgmax)[64] = (float(*)[64])(smem + 2048);   // 1024 B
    int   (*s_pgcol)[64] = (int(*)[64])(smem + 3072);     // 1024 B
    float (*s_psum)[64]  = (float(*)[64])(smem + 4096);   // 1024 B
    float* s_fmax  = (float*)(smem + 5120);               // 256 B
    float* s_fsum  = (float*)(smem + 5376);               // 256 B
    int*   s_fgcol = (int*)(smem + 5632);                 // 256 B
    float* s_bins  = (float*)(smem + 5888);               // 1280 B (ends 7168)
    int*   s_last  = (int*)(smem + 7168);
    float* s_red   = (float*)(smem + 7184);               // 4 floats (ends 7200 < 40960)

    int tid = threadIdx.x;
    int bx = blockIdx.x;
    int g  = (bx >> 3) & 1;                  // group 0/1; g-pair lands on same XCD
    int rb = (bx & 7) | ((bx >> 4) << 3);    // row-stripe 0..511 (bijective remap)
    int r0 = rb * 64;
    int w = tid >> 6;
    int l = tid & 63;
    int lrow = l >> 4;       // quad 0..3
    int lcol = l & 15;
    int mch = w >> 2;        // 0/1
    int s = w & 3;           // col slice
    int s5 = s * 5;

    f32x4 acc[2][5];
#pragma unroll
    for (int i = 0; i < 2; ++i)
#pragma unroll
        for (int j = 0; j < 5; ++j) acc[i][j] = (f32x4){0.f, 0.f, 0.f, 0.f};

    // A: lane holds A[m=lane&15][k=quad*8+j]; chunk i row = r0 + mch*32 + i*16 + lcol
    const float* xb0 = x + (size_t)(r0 + mch * 32 + lcol) * D_K + lrow * 8;
    const float* xb1 = xb0 + 16 * D_K;

    // async stage of the (kc, g) B tile into buf: 40960 B = 2560 x 16 B, 512 threads -> 5 each
    auto stage = [&](int kc, int buf) {
        const char* src = (const char*)(WB + (size_t)(kc * 2 + g) * TILE_HALVES);
        char* dst = smem + buf * 40960;
#pragma unroll
        for (int kk = 0; kk < 5; ++kk) {
            int u = tid + kk * 512;
            __builtin_amdgcn_global_load_lds((as1cv)(src + (size_t)u * 16),
                                             (as3v)(dst + u * 16), 16, 0, 0);
        }
    };

    stage(0, 0);
    f32x4 a00 = *(const f32x4*)xb0, a01 = *(const f32x4*)(xb0 + 4);
    f32x4 a10 = *(const f32x4*)xb1, a11 = *(const f32x4*)(xb1 + 4);

    for (int kc = 0; kc < KC_N; ++kc) {
        int cur = kc & 1;
        __syncthreads();   // drains vmcnt: buf[cur] staged, A(kc) regs ready;
                           // prior iteration's readers of buf[cur^1] are done
        f32x4 n00, n01, n10, n11;
        if (kc < KC_N - 1) {
            stage(kc + 1, cur ^ 1);             // drained at NEXT barrier (full phase later)
            n00 = *(const f32x4*)(xb0 + (kc + 1) * 32);
            n01 = *(const f32x4*)(xb0 + (kc + 1) * 32 + 4);
            n10 = *(const f32x4*)(xb1 + (kc + 1) * 32);
            n11 = *(const f32x4*)(xb1 + (kc + 1) * 32 + 4);
        }

        // convert current A (VALU; overlaps the just-issued prefetch)
        f16x8 ah[2], al[2];
#pragma unroll
        for (int j = 0; j < 4; ++j) {
            float f;
            _Float16 h;
            f = a00[j]; h = (_Float16)f; ah[0][j] = h;     al[0][j] = (_Float16)(f - (float)h);
            f = a01[j]; h = (_Float16)f; ah[0][4 + j] = h; al[0][4 + j] = (_Float16)(f - (float)h);
            f = a10[j]; h = (_Float16)f; ah[1][j] = h;     al[1][j] = (_Float16)(f - (float)h);
            f = a11[j]; h = (_Float16)f; ah[1][4 + j] = h; al[1][4 + j] = (_Float16)(f - (float)h);
        }

        // MFMA: 3-product fp16x2 (hh + lh + hl), B frags from LDS buf[cur]
        const _Float16* sBc = (const _Float16*)(smem + cur * 40960);
#pragma unroll
        for (int j = 0; j < 5; ++j) {
            int ncl = s5 + j;
            f16x8 bh = *(const f16x8*)(sBc + ncl * 512 + l * 8);
            f16x8 bl = *(const f16x8*)(sBc + HALF_TILE + ncl * 512 + l * 8);
            acc[0][j] = __builtin_amdgcn_mfma_f32_16x16x32_f16(ah[0], bh, acc[0][j], 0, 0, 0);
            acc[0][j] = __builtin_amdgcn_mfma_f32_16x16x32_f16(al[0], bh, acc[0][j], 0, 0, 0);
            acc[0][j] = __builtin_amdgcn_mfma_f32_16x16x32_f16(ah[0], bl, acc[0][j], 0, 0, 0);
            acc[1][j] = __builtin_amdgcn_mfma_f32_16x16x32_f16(ah[1], bh, acc[1][j], 0, 0, 0);
            acc[1][j] = __builtin_amdgcn_mfma_f32_16x16x32_f16(al[1], bh, acc[1][j], 0, 0, 0);
            acc[1][j] = __builtin_amdgcn_mfma_f32_16x16x32_f16(ah[1], bl, acc[1][j], 0, 0, 0);
        }
        if (kc < KC_N - 1) { a00 = n00; a01 = n01; a10 = n10; a11 = n11; }
    }

    // bias (zeros in setup, kept for correctness)
#pragma unroll
    for (int j = 0; j < 5; ++j) {
        float bb = bias[g * 320 + (s5 + j) * 16 + lcol];
#pragma unroll
        for (int i = 0; i < 2; ++i)
#pragma unroll
            for (int r = 0; r < 4; ++r) acc[i][j][r] += bb;
    }

    // ---------------- epilogue (one group per block; cols local 0..319) ----------------
    // E1: per-wave partial (max,argmax) of logits and logits+gumbel over the 80-col slice
#pragma unroll
    for (int i = 0; i < 2; ++i) {
#pragma unroll
        for (int r = 0; r < 4; ++r) {
            int row = mch * 32 + i * 16 + lrow * 4 + r;   // C/D: row = quad*4 + reg, col = lane&15
            float vmax = -3.4e38f; int vcol = 0;
            float gmax = -3.4e38f; int gcol = 0;
            const float* np = noise + (size_t)(r0 + row) * GK + g * 320 + s5 * 16 + lcol;
#pragma unroll
            for (int j = 0; j < 5; ++j) {
                float v = acc[i][j][r];
                int c = (s5 + j) * 16 + lcol;             // local col in group
                if (v > vmax) { vmax = v; vcol = c; }
                float u = np[j * 16] * (1.0f - 2e-6f) + 1e-6f;
                float gn = -__logf(-__logf(u));
                float z = v + gn;    // argmax((logits+g)/TAU) == argmax(logits+g)
                if (z > gmax) { gmax = z; gcol = c; }
            }
#pragma unroll
            for (int off = 1; off < 16; off <<= 1) {
                float ov = __shfl_xor(vmax, off); int oc = __shfl_xor(vcol, off);
                if (ov > vmax || (ov == vmax && oc < vcol)) { vmax = ov; vcol = oc; }
                float og = __shfl_xor(gmax, off); int ogc = __shfl_xor(gcol, off);
                if (og > gmax || (og == gmax && ogc < gcol)) { gmax = og; gcol = ogc; }
            }
            if (lcol == 0) {
                s_pmax[s][row] = vmax; s_pcol[s][row] = vcol;
                s_pgmax[s][row] = gmax; s_pgcol[s][row] = gcol;
            }
        }
    }
    if (tid < 320) s_bins[tid] = 0.0f;
    __syncthreads();

    // E2: combine 4 slices per row (ascending col = reference tie-break); hard-count atomic
    if (tid < 64) {
        int row = tid;
        float vmax = -3.4e38f; int vcol = 0;
        float gmax = -3.4e38f; int gcol = 0;
        for (int ss = 0; ss < 4; ++ss) {
            float v = s_pmax[ss][row];
            if (v > vmax) { vmax = v; vcol = s_pcol[ss][row]; }
            float z = s_pgmax[ss][row];
            if (z > gmax) { gmax = z; gcol = s_pgcol[ss][row]; }
        }
        s_fmax[row] = vmax;
        s_fgcol[row] = gcol;
        atomicAdd(&counts[g * 320 + vcol], 1u);
    }
    __syncthreads();

    // E3: exp-sum per row
#pragma unroll
    for (int i = 0; i < 2; ++i) {
#pragma unroll
        for (int r = 0; r < 4; ++r) {
            int row = mch * 32 + i * 16 + lrow * 4 + r;
            float M = s_fmax[row];
            float sm = 0.f;
#pragma unroll
            for (int j = 0; j < 5; ++j) sm += __expf(acc[i][j][r] - M);
#pragma unroll
            for (int off = 1; off < 16; off <<= 1) sm += __shfl_xor(sm, off);
            if (lcol == 0) s_psum[s][row] = sm;
        }
    }
    __syncthreads();
    if (tid < 64) {
        float S = 0.f;
        for (int ss = 0; ss < 4; ++ss) S += s_psum[ss][tid];
        s_fsum[tid] = S;
    }
    __syncthreads();

    // E4: per-thread register partials per column, quad-combine via shfl, then ONE
    // collision-free 16-lane LDS atomic per j
    {
        float part[5] = {0.f, 0.f, 0.f, 0.f, 0.f};
#pragma unroll
        for (int i = 0; i < 2; ++i) {
#pragma unroll
            for (int r = 0; r < 4; ++r) {
                int row = mch * 32 + i * 16 + lrow * 4 + r;
                float M = s_fmax[row];
                float invS = 1.0f / s_fsum[row];
#pragma unroll
                for (int j = 0; j < 5; ++j)
                    part[j] += __expf(acc[i][j][r] - M) * invS;
            }
        }
#pragma unroll
        for (int j = 0; j < 5; ++j) {
            float p = part[j];
            p += __shfl_xor(p, 16);     // combine lrow bit 0
            p += __shfl_xor(p, 32);     // combine lrow bit 1
            if (lrow == 0) atomicAdd(&s_bins[(s5 + j) * 16 + lcol], p);
        }
    }
    __syncthreads();
    if (tid < 320) atomicAdd(&probsum[g * 320 + tid], s_bins[tid]);

    // E5: out[row, g*128:(g+1)*128] = cb[winner, :]  (y == y_hard in forward)
    {
        int row = tid >> 3, jj = tid & 7;     // 64 teams of 8 threads
        int wcol = g * 320 + s_fgcol[row];
        const f32x4* src = (const f32x4*)(cb + (size_t)wcol * 128);
        f32x4* dst = (f32x4*)(out + (size_t)(r0 + row) * 256 + g * 128);
#pragma unroll
        for (int k = 0; k < 4; ++k) dst[k * 8 + jj] = src[k * 8 + jj];
    }

    // ---------------- fused finalize: last block computes perplexities ----------------
    __syncthreads();                 // this block's global atomics drained (vmcnt)
    if (tid == 0) {
        __threadfence();
        unsigned prev = atomicAdd(ticket, 1u);
        *s_last = (prev == 1023u) ? 1 : 0;
    }
    __syncthreads();
    if (*s_last) {
        __threadfence();
        // waves 0..3 -> segment: 0:hard g0, 1:hard g1, 2:soft g0, 3:soft g1
        if (w < 4) {
            float v = 0.f;
#pragma unroll
            for (int k = 0; k < 5; ++k) {
                int idx = (w & 1) * 320 + l + 64 * k;
                float p;
                if (w < 2)
                    p = (float)__hip_atomic_load(&counts[idx], __ATOMIC_RELAXED,
                                                 __HIP_MEMORY_SCOPE_AGENT) * (1.0f / 32768.0f);
                else
                    p = __hip_atomic_load(&probsum[idx], __ATOMIC_RELAXED,
                                          __HIP_MEMORY_SCOPE_AGENT) * (1.0f / 32768.0f);
                v += p * logf(p + 1e-7f);
            }
#pragma unroll
            for (int off = 1; off < 64; off <<= 1) v += __shfl_xor(v, off);
            if (l == 0) s_red[w] = v;
        }
        __syncthreads();
        if (tid < 2) out2[tid] = expf(-s_red[tid * 2]) + expf(-s_red[tid * 2 + 1]);
    }
}

extern "C" void kernel_launch(void* const* d_in, const int* in_sizes, int n_in,
                              void* d_out, int out_size, void* d_ws, size_t ws_size,
                              hipStream_t stream) {
    const float* x     = (const float*)d_in[0];   // [16,2048,768]
    const float* W     = (const float*)d_in[1];   // [768,640]
    const float* b     = (const float*)d_in[2];   // [640]
    const float* cb    = (const float*)d_in[3];   // [1,640,128]
    const float* noise = (const float*)d_in[4];   // [32768,2,320]
    float* out = (float*)d_out;                   // 16*2048*256 floats + 2 scalars

    char* ws = (char*)d_ws;
    unsigned* counts = (unsigned*)ws;             // [640] u32
    float* probsum   = (float*)(ws + 2560);       // [640] f32
    unsigned* ticket = (unsigned*)(ws + 5120);    // [1] u32 (word 1280, zeroed by prep)
    _Float16* WB     = (_Float16*)(ws + 8192);    // 24*2*20480 halves = 1966080 B

    hipLaunchKernelGGL(prep_kernel, dim3(240), dim3(256), 0, stream, W, counts, WB);
    hipLaunchKernelGGL(main_kernel, dim3(1024), dim3(512), 0, stream,
                       x, b, noise, cb, WB, out, counts, probsum, ticket, out + 8388608);
}